// Round 2
// baseline (424.816 us; speedup 1.0000x reference)
//
#include <hip/hip_runtime.h>
#include <hip/hip_bf16.h>
#include <stdint.h>

#define SQL 2048
#define EMB 1024
#define NHD 16
#define HDD 64

typedef __bf16 bf16x8 __attribute__((ext_vector_type(8)));
typedef __bf16 bf16x4 __attribute__((ext_vector_type(4)));
typedef float f32x4 __attribute__((ext_vector_type(4)));

__device__ __forceinline__ f32x4 mfma16(bf16x8 a, bf16x8 b, f32x4 c) {
    return __builtin_amdgcn_mfma_f32_16x16x32_bf16(a, b, c, 0, 0, 0);
}

// async global->LDS, 16B per lane. lds must be wave-uniform base; HW adds lane*16.
__device__ __forceinline__ void gload_lds16(const __bf16* g, __bf16* lds) {
    __builtin_amdgcn_global_load_lds(
        (const __attribute__((address_space(1))) uint32_t*)g,
        (__attribute__((address_space(3))) uint32_t*)lds,
        16, 0, 0);
}

// ---------------- fused fp32 -> bf16 cast of all 5 tensors ----------------
// dst regions are contiguous in workspace: xb(2M) wq(1M) wk(1M) wv(1M) wo(1M) elems.
__global__ void cast5_kernel(const float* __restrict__ x, const float* __restrict__ wq,
                             const float* __restrict__ wk, const float* __restrict__ wv,
                             const float* __restrict__ wo, __bf16* __restrict__ out)
{
    int i = blockIdx.x * blockDim.x + threadIdx.x;   // float4 units; 1536K total
    const float* src; int off;
    if      (i < (512 << 10))  { src = x;  off = 0; }
    else if (i < (768 << 10))  { src = wq; off = 512 << 10; }
    else if (i < (1024 << 10)) { src = wk; off = 768 << 10; }
    else if (i < (1280 << 10)) { src = wv; off = 1024 << 10; }
    else                       { src = wo; off = 1280 << 10; }
    float4 v = ((const float4*)src)[i - off];
    bf16x4 o;
    o[0] = (__bf16)v.x; o[1] = (__bf16)v.y; o[2] = (__bf16)v.z; o[3] = (__bf16)v.w;
    ((bf16x4*)out)[i] = o;
}

// ---------------- GEMM: C = (A @ B^T + bias) * scale ----------------
// A: [M,K] bf16 row-major, B: [N,K] bf16 row-major. grid.z selects (B,bias,out,scale).
// 128x128 tile, BK=32, m97 structure: linear LDS + global_load_lds width-16 staging.
template<bool OUT_BF16>
__global__ __launch_bounds__(256, 2)
void gemm_bt(const __bf16* __restrict__ A,
             const __bf16* __restrict__ B0, const __bf16* __restrict__ B1, const __bf16* __restrict__ B2,
             const float* __restrict__ bias0, const float* __restrict__ bias1, const float* __restrict__ bias2,
             void* __restrict__ out0, void* __restrict__ out1, void* __restrict__ out2,
             float s0, float s1, float s2,
             int M, int N, int K)
{
    const __bf16* B = B0; const float* bias = bias0; void* Cout = out0; float cscale = s0;
    if (blockIdx.z == 1) { B = B1; bias = bias1; Cout = out1; cscale = s1; }
    if (blockIdx.z == 2) { B = B2; bias = bias2; Cout = out2; cscale = s2; }

    __shared__ __attribute__((aligned(16))) __bf16 As[128 * 32];
    __shared__ __attribute__((aligned(16))) __bf16 Bs[128 * 32];

    const int tid  = threadIdx.x;
    const int lane = tid & 63;
    const int wave = tid >> 6;
    const int lrow = lane & 15;
    const int quad = lane >> 4;
    const int bm = blockIdx.y * 128;
    const int bn = blockIdx.x * 128;
    const int wm = (wave >> 1) * 64;
    const int wn = (wave & 1) * 64;

    const f32x4 fzero = {0.f, 0.f, 0.f, 0.f};
    f32x4 acc[4][4];
#pragma unroll
    for (int i = 0; i < 4; i++)
#pragma unroll
        for (int j = 0; j < 4; j++) acc[i][j] = fzero;

    const int srow = (lane >> 2);        // 0..15 row within 16-row chunk
    const int scol = (lane & 3) * 8;     // 0,8,16,24 elem col

    for (int k0 = 0; k0 < K; k0 += 32) {
        __syncthreads();
#pragma unroll
        for (int i = 0; i < 2; i++) {
            int rbase = wave * 32 + i * 16;
            gload_lds16(&A[(size_t)(bm + rbase + srow) * K + k0 + scol], &As[rbase * 32]);
            gload_lds16(&B[(size_t)(bn + rbase + srow) * K + k0 + scol], &Bs[rbase * 32]);
        }
        __syncthreads();
        bf16x8 af[4], bfr[4];
#pragma unroll
        for (int i = 0; i < 4; i++) af[i]  = *(const bf16x8*)&As[(wm + i * 16 + lrow) * 32 + quad * 8];
#pragma unroll
        for (int i = 0; i < 4; i++) bfr[i] = *(const bf16x8*)&Bs[(wn + i * 16 + lrow) * 32 + quad * 8];
#pragma unroll
        for (int mi = 0; mi < 4; mi++)
#pragma unroll
            for (int ni = 0; ni < 4; ni++)
                acc[mi][ni] = mfma16(af[mi], bfr[ni], acc[mi][ni]);
    }

#pragma unroll
    for (int mi = 0; mi < 4; mi++) {
        int row = bm + wm + mi * 16 + quad * 4;
#pragma unroll
        for (int ni = 0; ni < 4; ni++) {
            int col = bn + wn + ni * 16 + lrow;
            float bv = bias[col];
#pragma unroll
            for (int r = 0; r < 4; r++) {
                float v = (acc[mi][ni][r] + bv) * cscale;
                if (OUT_BF16) ((__bf16*)Cout)[(size_t)(row + r) * N + col] = (__bf16)v;
                else          ((float*)Cout)[(size_t)(row + r) * N + col] = v;
            }
        }
    }
}

// ---------------- V transpose: Vt[e][s] = V[s][e] ----------------
__global__ __launch_bounds__(256, 2)
void transpose_v(const __bf16* __restrict__ V, __bf16* __restrict__ Vt) {
    __shared__ __attribute__((aligned(16))) __bf16 tile[64][72];
    const int tid = threadIdx.x;
    const int s0 = blockIdx.x * 64;
    const int c0 = blockIdx.y * 64;
#pragma unroll
    for (int i = 0; i < 2; i++) {
        int lin = tid + i * 256;
        int r  = lin >> 3;
        int cg = (lin & 7) << 3;
        *(bf16x8*)&tile[r][cg] = *(const bf16x8*)&V[(size_t)(s0 + r) * EMB + c0 + cg];
    }
    __syncthreads();
#pragma unroll
    for (int i = 0; i < 2; i++) {
        int lin = tid + i * 256;
        int c  = lin >> 3;
        int sg = (lin & 7) << 3;
        bf16x8 t;
#pragma unroll
        for (int j = 0; j < 8; j++) t[j] = tile[sg + j][c];
        *(bf16x8*)&Vt[(size_t)(c0 + c) * SQL + s0 + sg] = t;
    }
}

// ---------------- fused attention, no-staging / no-barrier inner loops ----------------
// K,V per head = 256KB each -> L2-resident; read fragments DIRECTLY from global
// (m169 lesson: don't LDS-stage cache-fit data). Swapped QK^T (mfma(K,Q)) keeps
// softmax lane-local. Waves split (q-half wq, k-half wk): each wave owns 32 q x 32 k
// of every 64-tile. Online (m,l) over disjoint k-sets combined once after pass 1;
// partial O summed across the wk-pair via LDS once at the end.
__global__ __launch_bounds__(256, 2)
void attn_kernel(const __bf16* __restrict__ Qg, const __bf16* __restrict__ Kg,
                 const __bf16* __restrict__ Vt, float* __restrict__ attn,
                 __bf16* __restrict__ ctx)
{
    __shared__ __attribute__((aligned(16))) __bf16 Ps[4][32][40];  // per-wave P [q][k]
    __shared__ float MLb[2][2][2][16][2];                          // [wk][wq][qg][q][m|l]
    __shared__ float Ored[64][66];                                 // O partial exchange

    const int tid  = threadIdx.x;
    const int lane = tid & 63;
    const int w    = tid >> 6;
    const int wq   = w & 1;      // q-half
    const int wk   = w >> 1;     // k-half
    const int lrow = lane & 15;
    const int quad = lane >> 4;
    const int h  = blockIdx.y;
    const int q0 = blockIdx.x * 64;
    const f32x4 fzero = {0.f, 0.f, 0.f, 0.f};

    // Q fragments: 2 q-groups x 2 d-slices (Q pre-scaled by 1/32 in QKV GEMM)
    bf16x8 qf[2][2];
#pragma unroll
    for (int qg = 0; qg < 2; qg++) {
        const size_t qoff = (size_t)(q0 + wq * 32 + qg * 16 + lrow) * EMB + h * HDD;
        qf[qg][0] = *(const bf16x8*)&Qg[qoff + quad * 8];
        qf[qg][1] = *(const bf16x8*)&Qg[qoff + 32 + quad * 8];
    }

    float m[2] = {-1e30f, -1e30f}, l[2] = {0.f, 0.f};

    // ---- pass 1: online (m,l) over this wave's k-columns; NO barriers ----
    for (int k0 = 0; k0 < SQL; k0 += 64) {
        f32x4 st[2][2];
#pragma unroll
        for (int kt = 0; kt < 2; kt++) {
            const __bf16* kp = &Kg[(size_t)(k0 + wk * 32 + kt * 16 + lrow) * EMB + h * HDD];
            bf16x8 b0 = *(const bf16x8*)&kp[quad * 8];
            bf16x8 b1 = *(const bf16x8*)&kp[32 + quad * 8];
#pragma unroll
            for (int qg = 0; qg < 2; qg++) {
                f32x4 a = mfma16(b0, qf[qg][0], fzero);   // D[k=quad*4+r][q=lane&15]
                st[qg][kt] = mfma16(b1, qf[qg][1], a);
            }
        }
#pragma unroll
        for (int qg = 0; qg < 2; qg++) {
            float tm = -1e30f;
#pragma unroll
            for (int kt = 0; kt < 2; kt++)
#pragma unroll
                for (int r = 0; r < 4; r++) tm = fmaxf(tm, st[qg][kt][r]);
            tm = fmaxf(tm, __shfl_xor(tm, 16));
            tm = fmaxf(tm, __shfl_xor(tm, 32));
            float mn = fmaxf(m[qg], tm);
            float rs = 0.f;
#pragma unroll
            for (int kt = 0; kt < 2; kt++)
#pragma unroll
                for (int r = 0; r < 4; r++) rs += __expf(st[qg][kt][r] - mn);
            rs += __shfl_xor(rs, 16);
            rs += __shfl_xor(rs, 32);
            l[qg] = l[qg] * __expf(m[qg] - mn) + rs;
            m[qg] = mn;
        }
    }

    // ---- combine (m,l) across the wk pair (disjoint k-sets: associative) ----
    if (quad == 0) {
#pragma unroll
        for (int qg = 0; qg < 2; qg++) {
            MLb[wk][wq][qg][lrow][0] = m[qg];
            MLb[wk][wq][qg][lrow][1] = l[qg];
        }
    }
    __syncthreads();
    float rinv[2];
#pragma unroll
    for (int qg = 0; qg < 2; qg++) {
        float mo = MLb[wk ^ 1][wq][qg][lrow][0];
        float lo = MLb[wk ^ 1][wq][qg][lrow][1];
        float mf = fmaxf(m[qg], mo);
        float lf = l[qg] * __expf(m[qg] - mf) + lo * __expf(mo - mf);
        m[qg] = mf;
        rinv[qg] = 1.f / lf;
    }

    f32x4 o[2][4];
#pragma unroll
    for (int qg = 0; qg < 2; qg++)
#pragma unroll
        for (int nt = 0; nt < 4; nt++) o[qg][nt] = fzero;

    float* arow[2];
#pragma unroll
    for (int qg = 0; qg < 2; qg++)
        arow[qg] = attn + (size_t)h * SQL * SQL + (size_t)(q0 + wq * 32 + qg * 16 + lrow) * SQL;

    // ---- pass 2: recompute S, write attn, O += P @ V; NO barriers ----
    for (int k0 = 0; k0 < SQL; k0 += 64) {
        // V fragments issued early (independent of QK chain -> latency overlap)
        bf16x8 vf[4];
#pragma unroll
        for (int nt = 0; nt < 4; nt++)
            vf[nt] = *(const bf16x8*)&Vt[(size_t)(h * HDD + nt * 16 + lrow) * SQL + k0 + wk * 32 + quad * 8];

#pragma unroll
        for (int kt = 0; kt < 2; kt++) {
            const __bf16* kp = &Kg[(size_t)(k0 + wk * 32 + kt * 16 + lrow) * EMB + h * HDD];
            bf16x8 b0 = *(const bf16x8*)&kp[quad * 8];
            bf16x8 b1 = *(const bf16x8*)&kp[32 + quad * 8];
#pragma unroll
            for (int qg = 0; qg < 2; qg++) {
                f32x4 a = mfma16(b0, qf[qg][0], fzero);
                a = mfma16(b1, qf[qg][1], a);
                f32x4 pv; bf16x4 pb;
#pragma unroll
                for (int r = 0; r < 4; r++) {
                    float p = __expf(a[r] - m[qg]) * rinv[qg];
                    pv[r] = p; pb[r] = (__bf16)p;
                }
                *(f32x4*)&arow[qg][k0 + wk * 32 + kt * 16 + quad * 4] = pv;
                *(bf16x4*)&Ps[w][qg * 16 + lrow][kt * 16 + quad * 4] = pb;
            }
        }
        // wave-local P readback (in-order ds ops within a wave; no barrier)
        bf16x8 pf[2];
#pragma unroll
        for (int qg = 0; qg < 2; qg++)
            pf[qg] = *(const bf16x8*)&Ps[w][qg * 16 + lrow][quad * 8];
#pragma unroll
        for (int nt = 0; nt < 4; nt++)
#pragma unroll
            for (int qg = 0; qg < 2; qg++)
                o[qg][nt] = mfma16(pf[qg], vf[nt], o[qg][nt]);
    }

    // ---- sum partial O across the wk pair, write ctx ----
    if (wk == 1) {
#pragma unroll
        for (int qg = 0; qg < 2; qg++)
#pragma unroll
            for (int nt = 0; nt < 4; nt++)
#pragma unroll
                for (int r = 0; r < 4; r++)
                    Ored[wq * 32 + qg * 16 + quad * 4 + r][nt * 16 + lrow] = o[qg][nt][r];
    }
    __syncthreads();
    if (wk == 0) {
#pragma unroll
        for (int qg = 0; qg < 2; qg++)
#pragma unroll
            for (int nt = 0; nt < 4; nt++)
#pragma unroll
                for (int r = 0; r < 4; r++) {
                    int qrow = wq * 32 + qg * 16 + quad * 4 + r;
                    float v = o[qg][nt][r] + Ored[qrow][nt * 16 + lrow];
                    ctx[(size_t)(q0 + qrow) * EMB + h * HDD + nt * 16 + lrow] = (__bf16)v;
                }
    }
}

// ---------------- launch ----------------
extern "C" void kernel_launch(void* const* d_in, const int* in_sizes, int n_in,
                              void* d_out, int out_size, void* d_ws, size_t ws_size,
                              hipStream_t stream)
{
    const float* x  = (const float*)d_in[0];
    const float* Wq = (const float*)d_in[1];
    const float* bq = (const float*)d_in[2];
    const float* Wk = (const float*)d_in[3];
    const float* bk = (const float*)d_in[4];
    const float* Wv = (const float*)d_in[5];
    const float* bv = (const float*)d_in[6];
    const float* Wo = (const float*)d_in[7];
    const float* bo = (const float*)d_in[8];

    float* out  = (float*)d_out;
    float* attn = out + (size_t)SQL * EMB;

    const size_t M1 = 1u << 20;
    __bf16* wsb = (__bf16*)d_ws;
    __bf16* xb  = wsb;            // 2M
    __bf16* wqb = wsb + 2 * M1;   // 1M
    __bf16* wkb = wsb + 3 * M1;   // 1M
    __bf16* wvb = wsb + 4 * M1;   // 1M
    __bf16* wob = wsb + 5 * M1;   // 1M
    __bf16* Qb  = wsb + 6 * M1;   // 2M
    __bf16* Kb  = wsb + 8 * M1;   // 2M
    __bf16* Vb  = wsb + 10 * M1;  // 2M
    __bf16* Vtb = wsb + 12 * M1;  // 2M
    __bf16* ctb = wsb + 14 * M1;  // 2M

    // all 5 casts in one launch (destinations contiguous from wsb)
    cast5_kernel<<<6144, 256, 0, stream>>>(x, Wq, Wk, Wv, Wo, wsb);

    // Q,K,V = x @ W^T + b   (Q scaled by 1/32 = exact pow2)
    gemm_bt<true><<<dim3(EMB / 128, SQL / 128, 3), 256, 0, stream>>>(
        xb, wqb, wkb, wvb, bq, bk, bv,
        (void*)Qb, (void*)Kb, (void*)Vb,
        0.03125f, 1.0f, 1.0f, SQL, EMB, EMB);

    transpose_v<<<dim3(SQL / 64, EMB / 64), 256, 0, stream>>>(Vb, Vtb);

    attn_kernel<<<dim3(SQL / 64, NHD), 256, 0, stream>>>(Qb, Kb, Vtb, attn, ctb);

    // out = ctx @ Wo^T + bo  (fp32 output)
    gemm_bt<false><<<dim3(EMB / 128, SQL / 128, 1), 256, 0, stream>>>(
        ctb, wob, wob, wob, bo, bo, bo,
        (void*)out, (void*)out, (void*)out,
        1.0f, 1.0f, 1.0f, SQL, EMB, EMB);
}

// Round 3
// 413.906 us; speedup vs baseline: 1.0264x; 1.0264x over previous
//
#include <hip/hip_runtime.h>
#include <hip/hip_bf16.h>
#include <stdint.h>

#define SQL 2048
#define EMB 1024
#define NHD 16
#define HDD 64

typedef __bf16 bf16x8 __attribute__((ext_vector_type(8)));
typedef __bf16 bf16x4 __attribute__((ext_vector_type(4)));
typedef float f32x4 __attribute__((ext_vector_type(4)));
typedef float f32x16 __attribute__((ext_vector_type(16)));

__device__ __forceinline__ f32x4 mfma16(bf16x8 a, bf16x8 b, f32x4 c) {
    return __builtin_amdgcn_mfma_f32_16x16x32_bf16(a, b, c, 0, 0, 0);
}
__device__ __forceinline__ f32x16 mfma32(bf16x8 a, bf16x8 b, f32x16 c) {
    return __builtin_amdgcn_mfma_f32_32x32x16_bf16(a, b, c, 0, 0, 0);
}

// async global->LDS, 16B per lane. lds must be wave-uniform base; HW adds lane*16.
__device__ __forceinline__ void gload_lds16(const __bf16* g, __bf16* lds) {
    __builtin_amdgcn_global_load_lds(
        (const __attribute__((address_space(1))) uint32_t*)g,
        (__attribute__((address_space(3))) uint32_t*)lds,
        16, 0, 0);
}

// ---------------- fused fp32 -> bf16 cast of all 5 tensors ----------------
__global__ void cast5_kernel(const float* __restrict__ x, const float* __restrict__ wq,
                             const float* __restrict__ wk, const float* __restrict__ wv,
                             const float* __restrict__ wo, __bf16* __restrict__ out)
{
    int i = blockIdx.x * blockDim.x + threadIdx.x;   // float4 units; 1536K total
    const float* src; int off;
    if      (i < (512 << 10))  { src = x;  off = 0; }
    else if (i < (768 << 10))  { src = wq; off = 512 << 10; }
    else if (i < (1024 << 10)) { src = wk; off = 768 << 10; }
    else if (i < (1280 << 10)) { src = wv; off = 1024 << 10; }
    else                       { src = wo; off = 1280 << 10; }
    float4 v = ((const float4*)src)[i - off];
    bf16x4 o;
    o[0] = (__bf16)v.x; o[1] = (__bf16)v.y; o[2] = (__bf16)v.z; o[3] = (__bf16)v.w;
    ((bf16x4*)out)[i] = o;
}

// ---------------- GEMM: C = (A @ B^T + bias) * scale ---------------- (unchanged, verified)
template<bool OUT_BF16>
__global__ __launch_bounds__(256, 2)
void gemm_bt(const __bf16* __restrict__ A,
             const __bf16* __restrict__ B0, const __bf16* __restrict__ B1, const __bf16* __restrict__ B2,
             const float* __restrict__ bias0, const float* __restrict__ bias1, const float* __restrict__ bias2,
             void* __restrict__ out0, void* __restrict__ out1, void* __restrict__ out2,
             float s0, float s1, float s2,
             int M, int N, int K)
{
    const __bf16* B = B0; const float* bias = bias0; void* Cout = out0; float cscale = s0;
    if (blockIdx.z == 1) { B = B1; bias = bias1; Cout = out1; cscale = s1; }
    if (blockIdx.z == 2) { B = B2; bias = bias2; Cout = out2; cscale = s2; }

    __shared__ __attribute__((aligned(16))) __bf16 As[128 * 32];
    __shared__ __attribute__((aligned(16))) __bf16 Bs[128 * 32];

    const int tid  = threadIdx.x;
    const int lane = tid & 63;
    const int wave = tid >> 6;
    const int lrow = lane & 15;
    const int quad = lane >> 4;
    const int bm = blockIdx.y * 128;
    const int bn = blockIdx.x * 128;
    const int wm = (wave >> 1) * 64;
    const int wn = (wave & 1) * 64;

    const f32x4 fzero = {0.f, 0.f, 0.f, 0.f};
    f32x4 acc[4][4];
#pragma unroll
    for (int i = 0; i < 4; i++)
#pragma unroll
        for (int j = 0; j < 4; j++) acc[i][j] = fzero;

    const int srow = (lane >> 2);
    const int scol = (lane & 3) * 8;

    for (int k0 = 0; k0 < K; k0 += 32) {
        __syncthreads();
#pragma unroll
        for (int i = 0; i < 2; i++) {
            int rbase = wave * 32 + i * 16;
            gload_lds16(&A[(size_t)(bm + rbase + srow) * K + k0 + scol], &As[rbase * 32]);
            gload_lds16(&B[(size_t)(bn + rbase + srow) * K + k0 + scol], &Bs[rbase * 32]);
        }
        __syncthreads();
        bf16x8 af[4], bfr[4];
#pragma unroll
        for (int i = 0; i < 4; i++) af[i]  = *(const bf16x8*)&As[(wm + i * 16 + lrow) * 32 + quad * 8];
#pragma unroll
        for (int i = 0; i < 4; i++) bfr[i] = *(const bf16x8*)&Bs[(wn + i * 16 + lrow) * 32 + quad * 8];
#pragma unroll
        for (int mi = 0; mi < 4; mi++)
#pragma unroll
            for (int ni = 0; ni < 4; ni++)
                acc[mi][ni] = mfma16(af[mi], bfr[ni], acc[mi][ni]);
    }

#pragma unroll
    for (int mi = 0; mi < 4; mi++) {
        int row = bm + wm + mi * 16 + quad * 4;
#pragma unroll
        for (int ni = 0; ni < 4; ni++) {
            int col = bn + wn + ni * 16 + lrow;
            float bv = bias[col];
#pragma unroll
            for (int r = 0; r < 4; r++) {
                float v = (acc[mi][ni][r] + bv) * cscale;
                if (OUT_BF16) ((__bf16*)Cout)[(size_t)(row + r) * N + col] = (__bf16)v;
                else          ((float*)Cout)[(size_t)(row + r) * N + col] = v;
            }
        }
    }
}

// ---------------- V transpose: Vt[e][s] = V[s][e] ---------------- (unchanged)
__global__ __launch_bounds__(256, 2)
void transpose_v(const __bf16* __restrict__ V, __bf16* __restrict__ Vt) {
    __shared__ __attribute__((aligned(16))) __bf16 tile[64][72];
    const int tid = threadIdx.x;
    const int s0 = blockIdx.x * 64;
    const int c0 = blockIdx.y * 64;
#pragma unroll
    for (int i = 0; i < 2; i++) {
        int lin = tid + i * 256;
        int r  = lin >> 3;
        int cg = (lin & 7) << 3;
        *(bf16x8*)&tile[r][cg] = *(const bf16x8*)&V[(size_t)(s0 + r) * EMB + c0 + cg];
    }
    __syncthreads();
#pragma unroll
    for (int i = 0; i < 2; i++) {
        int lin = tid + i * 256;
        int c  = lin >> 3;
        int sg = (lin & 7) << 3;
        bf16x8 t;
#pragma unroll
        for (int j = 0; j < 8; j++) t[j] = tile[sg + j][c];
        *(bf16x8*)&Vt[(size_t)(c0 + c) * SQL + s0 + sg] = t;
    }
}

// ---------------- fused attention: 32x32 MFMA + swizzled dbuf gload_lds ----------------
// Swapped QK^T (mfma(K,Q)): lane owns q-col (lane&31), 16 k-values in regs ->
// softmax reduce = 15 in-reg ops + 1 shuffle. Waves split (wq,wk) quadrants:
// wave covers 32q x 32k of each 64-tile. K/V double-buffered in LDS via
// global_load_lds with pre-swizzled source (slot ^= row&7, G21 both-sides);
// reads use the same XOR -> conflict-free ds_read_b128. ONE barrier per tile.
// PV: mfma(Vt_frag, P_frag) -> per-wave P LDS buffer matches B-operand layout.
__global__ __launch_bounds__(256, 2)
void attn_kernel(const __bf16* __restrict__ Qg, const __bf16* __restrict__ Kg,
                 const __bf16* __restrict__ Vt, float* __restrict__ attn,
                 __bf16* __restrict__ ctx)
{
    __shared__ __attribute__((aligned(16))) __bf16 Ks[2][64 * 64];
    __shared__ __attribute__((aligned(16))) __bf16 Vs[2][64 * 64];   // Vs[d][k]
    __shared__ __attribute__((aligned(16))) __bf16 Ps[4][32 * 40];   // per-wave P^T-ish [q][k]
    __shared__ float MLb[2][2][32][2];                                // [wk][wq][q][m|l]
    __shared__ float Ored[64][66];                                    // [d][q] partial O

    const int tid  = threadIdx.x;
    const int lane = tid & 63;
    const int w    = tid >> 6;
    const int wq   = w & 1;
    const int wk   = w >> 1;
    const int l31  = lane & 31;
    const int hi   = lane >> 5;
    const int h  = blockIdx.y;
    const int q0 = blockIdx.x * 64;

    // staging: per gload call, 8 rows x 128B; lane i -> row i>>3, phys slot i&7.
    // phys slot sp holds data slot sp^(row&7)  => source pre-swizzle.
    const int srow  = lane >> 3;
    const int sslot = (lane & 7) ^ (srow & 7);

    auto stageK = [&](int buf, int k0) {
#pragma unroll
        for (int j = 0; j < 2; j++) {
            int r = w * 16 + j * 8;
            gload_lds16(&Kg[(size_t)(k0 + r + srow) * EMB + h * HDD + sslot * 8],
                        &Ks[buf][r * 64]);
        }
    };
    auto stageV = [&](int buf, int k0) {
#pragma unroll
        for (int j = 0; j < 2; j++) {
            int r = w * 16 + j * 8;
            gload_lds16(&Vt[(size_t)(h * HDD + r + srow) * SQL + k0 + sslot * 8],
                        &Vs[buf][r * 64]);
        }
    };

    // Q B-fragments (col = this lane's q row), 4 d-slices of 16; Q pre-scaled 1/32
    bf16x8 qf[4];
    {
        const __bf16* qp = &Qg[(size_t)(q0 + wq * 32 + l31) * EMB + h * HDD + hi * 8];
#pragma unroll
        for (int ds = 0; ds < 4; ds++) qf[ds] = *(const bf16x8*)&qp[ds * 16];
    }

    const f32x16 Z16 = {0.f,0.f,0.f,0.f,0.f,0.f,0.f,0.f,0.f,0.f,0.f,0.f,0.f,0.f,0.f,0.f};
    const int krowoff = (wk * 32 + l31) * 64;   // elem offset of this lane's K row
    const int lane7   = lane & 7;

    float sm_m = -1e30f, sm_l = 0.f;
    int buf = 0;

    // ---- pass 1: online (m,l); stage(t+1) overlaps compute(t); 1 barrier/tile ----
    stageK(0, 0);
    __syncthreads();
    for (int t = 0; t < 32; t++) {
        if (t < 31) stageK(buf ^ 1, (t + 1) * 64);
        f32x16 s = Z16;
#pragma unroll
        for (int ds = 0; ds < 4; ds++) {
            bf16x8 kf = *(const bf16x8*)&Ks[buf][krowoff + ((((ds << 1) | hi) ^ lane7) << 3)];
            s = mfma32(kf, qf[ds], s);   // D[k_local][q=lane&31]
        }
        float tm = s[0];
#pragma unroll
        for (int r = 1; r < 16; r++) tm = fmaxf(tm, s[r]);
        tm = fmaxf(tm, __shfl_xor(tm, 32));
        float mn = fmaxf(sm_m, tm);
        float rs = 0.f;
#pragma unroll
        for (int r = 0; r < 16; r++) rs += __expf(s[r] - mn);
        rs += __shfl_xor(rs, 32);
        sm_l = sm_l * __expf(sm_m - mn) + rs;
        sm_m = mn;
        __syncthreads();   // drains vmcnt (stages landed) + buffer handoff
        buf ^= 1;
    }

    // ---- combine (m,l) across the wk pair; overlap pass-2 tile-0 staging ----
    if (lane < 32) { MLb[wk][wq][lane][0] = sm_m; MLb[wk][wq][lane][1] = sm_l; }
    stageK(0, 0);
    stageV(0, 0);
    __syncthreads();
    float rinv;
    {
        float mo = MLb[wk ^ 1][wq][l31][0];
        float lo = MLb[wk ^ 1][wq][l31][1];
        float mf = fmaxf(sm_m, mo);
        float lf = sm_l * __expf(sm_m - mf) + lo * __expf(mo - mf);
        sm_m = mf;
        rinv = 1.f / lf;
    }

    f32x16 o0 = Z16, o1 = Z16;
    float* __restrict__ arow = attn + (size_t)h * SQL * SQL + (size_t)(q0 + wq * 32 + l31) * SQL;
    const int vrow0 = l31 * 64;          // dt=0 rows
    const int vrow1 = (32 + l31) * 64;   // dt=1 rows
    const int psrow = l31 * 40;

    // ---- pass 2: recompute S, write attn, O += P@V; 1 barrier/tile ----
    buf = 0;
    for (int t = 0; t < 32; t++) {
        const int k0 = t * 64;
        if (t < 31) { stageK(buf ^ 1, k0 + 64); stageV(buf ^ 1, k0 + 64); }
        f32x16 s = Z16;
#pragma unroll
        for (int ds = 0; ds < 4; ds++) {
            bf16x8 kf = *(const bf16x8*)&Ks[buf][krowoff + ((((ds << 1) | hi) ^ lane7) << 3)];
            s = mfma32(kf, qf[ds], s);
        }
        // P = exp(S-m)*rinv; attn write (f32x4, consecutive k) + Ps write (bf16x4)
#pragma unroll
        for (int g = 0; g < 4; g++) {
            f32x4 pv; bf16x4 pb;
#pragma unroll
            for (int i = 0; i < 4; i++) {
                float p = __expf(s[g * 4 + i] - sm_m) * rinv;
                pv[i] = p; pb[i] = (__bf16)p;
            }
            *(f32x4*)&arow[k0 + wk * 32 + g * 8 + hi * 4] = pv;
            *(bf16x4*)&Ps[w][psrow + g * 8 + hi * 4] = pb;
        }
        // PV: A=V^T rows d, B=P^T cols q (wave-local Ps, in-order ds ops)
#pragma unroll
        for (int kt = 0; kt < 2; kt++) {
            bf16x8 pf = *(const bf16x8*)&Ps[w][psrow + kt * 16 + hi * 8];
            int vslot = (((wk << 2) | (kt << 1) | hi) ^ lane7) << 3;
            bf16x8 v0 = *(const bf16x8*)&Vs[buf][vrow0 + vslot];
            bf16x8 v1 = *(const bf16x8*)&Vs[buf][vrow1 + vslot];
            o0 = mfma32(v0, pf, o0);
            o1 = mfma32(v1, pf, o1);
        }
        __syncthreads();
        buf ^= 1;
    }

    // ---- sum partial O across the wk pair, write ctx ----
    if (wk == 1) {
#pragma unroll
        for (int g = 0; g < 4; g++)
#pragma unroll
            for (int i = 0; i < 4; i++) {
                int dl = i + g * 8 + hi * 4;
                Ored[dl][wq * 32 + l31]      = o0[g * 4 + i];
                Ored[32 + dl][wq * 32 + l31] = o1[g * 4 + i];
            }
    }
    __syncthreads();
    if (wk == 0) {
        __bf16* crow = &ctx[(size_t)(q0 + wq * 32 + l31) * EMB + h * HDD];
#pragma unroll
        for (int g = 0; g < 4; g++) {
            bf16x4 c0, c1;
#pragma unroll
            for (int i = 0; i < 4; i++) {
                int dl = i + g * 8 + hi * 4;
                c0[i] = (__bf16)(o0[g * 4 + i] + Ored[dl][wq * 32 + l31]);
                c1[i] = (__bf16)(o1[g * 4 + i] + Ored[32 + dl][wq * 32 + l31]);
            }
            *(bf16x4*)&crow[g * 8 + hi * 4]      = c0;
            *(bf16x4*)&crow[32 + g * 8 + hi * 4] = c1;
        }
    }
}

// ---------------- launch ----------------
extern "C" void kernel_launch(void* const* d_in, const int* in_sizes, int n_in,
                              void* d_out, int out_size, void* d_ws, size_t ws_size,
                              hipStream_t stream)
{
    const float* x  = (const float*)d_in[0];
    const float* Wq = (const float*)d_in[1];
    const float* bq = (const float*)d_in[2];
    const float* Wk = (const float*)d_in[3];
    const float* bk = (const float*)d_in[4];
    const float* Wv = (const float*)d_in[5];
    const float* bv = (const float*)d_in[6];
    const float* Wo = (const float*)d_in[7];
    const float* bo = (const float*)d_in[8];

    float* out  = (float*)d_out;
    float* attn = out + (size_t)SQL * EMB;

    const size_t M1 = 1u << 20;
    __bf16* wsb = (__bf16*)d_ws;
    __bf16* xb  = wsb;            // 2M
    __bf16* wqb = wsb + 2 * M1;   // 1M
    __bf16* wkb = wsb + 3 * M1;   // 1M
    __bf16* wvb = wsb + 4 * M1;   // 1M
    __bf16* wob = wsb + 5 * M1;   // 1M
    __bf16* Qb  = wsb + 6 * M1;   // 2M
    __bf16* Kb  = wsb + 8 * M1;   // 2M
    __bf16* Vb  = wsb + 10 * M1;  // 2M
    __bf16* Vtb = wsb + 12 * M1;  // 2M
    __bf16* ctb = wsb + 14 * M1;  // 2M

    cast5_kernel<<<6144, 256, 0, stream>>>(x, Wq, Wk, Wv, Wo, wsb);

    // Q,K,V = x @ W^T + b   (Q scaled by 1/32 = exact pow2)
    gemm_bt<true><<<dim3(EMB / 128, SQL / 128, 3), 256, 0, stream>>>(
        xb, wqb, wkb, wvb, bq, bk, bv,
        (void*)Qb, (void*)Kb, (void*)Vb,
        0.03125f, 1.0f, 1.0f, SQL, EMB, EMB);

    transpose_v<<<dim3(SQL / 64, EMB / 64), 256, 0, stream>>>(Vb, Vtb);

    attn_kernel<<<dim3(SQL / 64, NHD), 256, 0, stream>>>(Qb, Kb, Vtb, attn, ctb);

    // out = ctx @ Wo^T + bo  (fp32 output)
    gemm_bt<false><<<dim3(EMB / 128, SQL / 128, 1), 256, 0, stream>>>(
        ctb, wob, wob, wob, bo, bo, bo,
        (void*)out, (void*)out, (void*)out,
        1.0f, 1.0f, 1.0f, SQL, EMB, EMB);
}